// Round 15
// baseline (297.398 us; speedup 1.0000x reference)
//
#include <hip/hip_runtime.h>
#include <hip/hip_fp16.h>

// GCN 2-layer. N=250000, E=4000000, 18 -> 16 -> 1.
// R12: feature-split agg1 for L2 residency. R11 landed 254us; agg1 (58us)
// fetches its full logical volume (148MB @ 2.6TB/s): the 8MB fp16 hs1
// working set exceeds the 4MB/XCD L2 and the csr_src stream evicts it.
// Fix: split agg1 into two passes over 4MB half-feature arrays (hs1a=f0-7,
// hs1b=f8-15, 16B rows) -> resident per XCD after a 32MB compulsory sweep;
// csr_src/rowp streams use nontemporal (evict-first) loads to protect it.
// relu+W2-dot epilogue splits per-feature: passA stores partial[n], passB
// completes and writes hs2. bhist/bscan/bplace/csr/agg2 frozen from R11.
//
// out[d] = dis[d] * (sum_{s->d} hs[s] + hs[d]) + bias, hs pre-scaled by dis.

#define NB_BITS 8
#define BN (1 << NB_BITS)       // 256 nodes per agg bucket (agg1 grid)
#define SB_BITS 9
#define SBN (1 << SB_BITS)      // 512 nodes per sort bin
#define NSB 512                 // padded bin count (489 used)
#define BIN_TPB 512
#define BIN_CHUNK 8192
#define AGG_TPB 512

// per-block LDS histogram of dst sort-bins -> global bcnt
__global__ void bhist_kernel(const int* __restrict__ dst, int* __restrict__ bcnt, int E) {
    __shared__ int cnt[NSB];
    int t = threadIdx.x;        // BIN_TPB == NSB == 512
    cnt[t] = 0;
    __syncthreads();
    int base = blockIdx.x * BIN_CHUNK;
    int end = min(base + BIN_CHUNK, E);
#pragma unroll 4
    for (int e = base + t; e < end; e += BIN_TPB)
        atomicAdd(&cnt[dst[e] >> SB_BITS], 1);
    __syncthreads();
    if (cnt[t] > 0) atomicAdd(&bcnt[t], cnt[t]);
}

// exclusive scan of bcnt[NSB] -> bstart, cursor
__global__ void bscan_kernel(const int* __restrict__ bcnt, int* __restrict__ bstart,
                             int* __restrict__ cursor) {
    __shared__ int s[NSB];
    int t = threadIdx.x;  // NSB threads
    int v = bcnt[t];
    s[t] = v;
    __syncthreads();
    for (int off = 1; off < NSB; off <<= 1) {
        int add = (t >= off) ? s[t - off] : 0;
        __syncthreads();
        s[t] += add;
        __syncthreads();
    }
    int excl = s[t] - v;
    bstart[t] = excl;
    cursor[t] = excl;
    if (t == NSB - 1) bstart[NSB] = s[t];
}

// place edges with block-local counting sort -> coalesced run writes.
// pairs value = (src<<9 | dst&511), bin-contiguous in global memory.
__global__ void bplace_kernel(const int* __restrict__ src, const int* __restrict__ dst,
                              int* __restrict__ cursor, int* __restrict__ pairs, int E) {
    __shared__ int cnt[NSB];
    __shared__ int lstart[NSB];
    __shared__ int lcur[NSB];
    __shared__ int gbase[NSB];
    __shared__ int lbuf[BIN_CHUNK];            // 32KB
    __shared__ unsigned short lbin[BIN_CHUNK]; // 16KB
    int t = threadIdx.x;
    int base = blockIdx.x * BIN_CHUNK;
    int end = min(base + BIN_CHUNK, E);
    cnt[t] = 0;
    __syncthreads();
#pragma unroll 4
    for (int e = base + t; e < end; e += BIN_TPB)
        atomicAdd(&cnt[dst[e] >> SB_BITS], 1);
    __syncthreads();
    // inclusive scan of cnt (Hillis-Steele in lstart)
    int v = cnt[t];
    lstart[t] = v;
    __syncthreads();
    for (int off = 1; off < NSB; off <<= 1) {
        int add = (t >= off) ? lstart[t - off] : 0;
        __syncthreads();
        lstart[t] += add;
        __syncthreads();
    }
    int excl = lstart[t] - v;   // own-index reads only below: no hazard
    lstart[t] = excl;
    lcur[t] = excl;
    gbase[t] = (v > 0) ? atomicAdd(&cursor[t], v) : 0;
    __syncthreads();
    // scatter into LDS in bin-sorted order
#pragma unroll 2
    for (int e = base + t; e < end; e += BIN_TPB) {
        int d = dst[e], s = src[e];
        int b = d >> SB_BITS;
        int pos = atomicAdd(&lcur[b], 1);
        lbuf[pos] = (s << SB_BITS) | (d & (SBN - 1));
        lbin[pos] = (unsigned short)b;
    }
    __syncthreads();
    // copy out: consecutive i within a bin -> consecutive global addresses
    int n = end - base;
#pragma unroll 4
    for (int i = t; i < n; i += BIN_TPB) {
        int b = lbin[i];
        pairs[gbase[b] + (i - lstart[b])] = lbuf[i];
    }
}

// per-bin CSR build: count per dst (int LDS atomics), scan, place srcs in
// dst-sorted order. Emits rowp, csr_src, dis = rsqrt(deg+1).
__global__ void csr_kernel(const int* __restrict__ pairs, const int* __restrict__ bstart,
                           int* __restrict__ rowp, int* __restrict__ csr_src,
                           float* __restrict__ dis, int N) {
    __shared__ int cnt[SBN];
    __shared__ int tmp[SBN];
    int b = blockIdx.x, t = threadIdx.x;   // TPB == SBN == 512
    int s0 = bstart[b], s1 = bstart[b + 1];
    cnt[t] = 0;
    __syncthreads();
#pragma unroll 4
    for (int e = s0 + t; e < s1; e += SBN)
        atomicAdd(&cnt[pairs[e] & (SBN - 1)], 1);
    __syncthreads();
    int v = cnt[t];
    tmp[t] = v;
    __syncthreads();
    for (int off = 1; off < SBN; off <<= 1) {
        int add = (t >= off) ? tmp[t - off] : 0;
        __syncthreads();
        tmp[t] += add;
        __syncthreads();
    }
    int nbase = b << SB_BITS;
    int start = s0 + tmp[t] - v;   // exclusive within bin, global offset
    rowp[nbase + t] = start;
    int n = nbase + t;
    if (n < N) dis[n] = rsqrtf((float)v + 1.0f);
    cnt[t] = start;                // reuse as placement cursor
    if (t == 0) rowp[nbase + SBN] = s1;  // boundary (dup of next bin's first)
    __syncthreads();
#pragma unroll 4
    for (int e = s0 + t; e < s1; e += SBN) {
        int pv = pairs[e];
        int pos = atomicAdd(&cnt[pv & (SBN - 1)], 1);
        csr_src[pos] = pv >> SB_BITS;
    }
}

// hs1a[n,f<8], hs1b[n,f-8>=0] = fp16( (x[n] @ W1)[f] * dis[n] ) -- 16B rows
__global__ void h1_kernel(const float* __restrict__ x, const float* __restrict__ W1,
                          const float* __restrict__ dis, __half* __restrict__ hs1a,
                          __half* __restrict__ hs1b, int N) {
    __shared__ float w[18 * 16];
    for (int i = threadIdx.x; i < 18 * 16; i += blockDim.x) w[i] = W1[i];
    __syncthreads();
    int n = blockIdx.x * blockDim.x + threadIdx.x;
    if (n >= N) return;
    const float2* x2 = (const float2*)(x + (size_t)n * 18);
    float xv[18];
#pragma unroll
    for (int k = 0; k < 9; k++) {
        float2 v = x2[k];
        xv[2 * k] = v.x;
        xv[2 * k + 1] = v.y;
    }
    float d = dis[n];
    float acc[16];
#pragma unroll
    for (int f = 0; f < 16; f++) acc[f] = 0.0f;
#pragma unroll
    for (int k = 0; k < 18; k++) {
        float xk = xv[k];
#pragma unroll
        for (int f = 0; f < 16; f++) acc[f] = fmaf(xk, w[k * 16 + f], acc[f]);
    }
    unsigned int u[8];
#pragma unroll
    for (int q = 0; q < 8; q++) {
        unsigned int lo = __half_as_ushort(__float2half_rn(acc[2 * q] * d));
        unsigned int hi = __half_as_ushort(__float2half_rn(acc[2 * q + 1] * d));
        u[q] = lo | (hi << 16);
    }
    *(uint4*)(hs1a + (size_t)n * 8) = make_uint4(u[0], u[1], u[2], u[3]);
    *(uint4*)(hs1b + (size_t)n * 8) = make_uint4(u[4], u[5], u[6], u[7]);
}

// layer-1 pass A (features 0-7): CSR, one node per 8-lane group, register
// accumulation from the L2-resident 4MB hs1a; csr/rowp via nontemporal loads.
// partial[n] = sum_{f<8} relu(d*(acc+self)+b1[f]) * W2[f]
__global__ void agg1a_kernel(const int* __restrict__ csr_src, const int* __restrict__ rowp,
                             const __half* __restrict__ hs1a, const float* __restrict__ dis,
                             const float* __restrict__ b1, const float* __restrict__ W2,
                             float* __restrict__ partial, int N) {
    int b = blockIdx.x, t = threadIdx.x;
    int f = t & 7;
    int g = t >> 3;                 // 0..63 groups
    float bbf = b1[f], wwf = W2[f];
    int nbase = b << NB_BITS;
    for (int nl = g; nl < BN; nl += AGG_TPB / 8) {
        int n = nbase + nl;
        if (n >= N) continue;
        int r0 = __builtin_nontemporal_load(rowp + n);
        int r1 = __builtin_nontemporal_load(rowp + n + 1);
        float a = 0.f;
#pragma unroll 4
        for (int r = r0; r < r1; ++r) {
            int s = __builtin_nontemporal_load(csr_src + r);
            a += __half2float(hs1a[(size_t)s * 8 + f]);
        }
        float d = dis[n];
        float self = __half2float(hs1a[(size_t)n * 8 + f]);
        float p = fmaxf(d * (a + self) + bbf, 0.f) * wwf;
        p += __shfl_xor(p, 1);
        p += __shfl_xor(p, 2);
        p += __shfl_xor(p, 4);
        if (f == 0) partial[n] = p;
    }
}

// layer-1 pass B (features 8-15): completes the dot, writes hs2.
__global__ void agg1b_kernel(const int* __restrict__ csr_src, const int* __restrict__ rowp,
                             const __half* __restrict__ hs1b, const float* __restrict__ dis,
                             const float* __restrict__ b1, const float* __restrict__ W2,
                             const float* __restrict__ partial, float* __restrict__ hs2,
                             int N) {
    int b = blockIdx.x, t = threadIdx.x;
    int f = t & 7;
    int g = t >> 3;
    float bbf = b1[8 + f], wwf = W2[8 + f];
    int nbase = b << NB_BITS;
    for (int nl = g; nl < BN; nl += AGG_TPB / 8) {
        int n = nbase + nl;
        if (n >= N) continue;
        int r0 = __builtin_nontemporal_load(rowp + n);
        int r1 = __builtin_nontemporal_load(rowp + n + 1);
        float a = 0.f;
#pragma unroll 4
        for (int r = r0; r < r1; ++r) {
            int s = __builtin_nontemporal_load(csr_src + r);
            a += __half2float(hs1b[(size_t)s * 8 + f]);
        }
        float d = dis[n];
        float self = __half2float(hs1b[(size_t)n * 8 + f]);
        float p = fmaxf(d * (a + self) + bbf, 0.f) * wwf;
        p += __shfl_xor(p, 1);
        p += __shfl_xor(p, 2);
        p += __shfl_xor(p, 4);
        if (f == 0) hs2[n] = (partial[n] + p) * d;
    }
}

// layer-2: CSR, one node per 16-lane group; lanes split the run, shfl reduce.
// hs2 is 1MB -> L2-resident gather.
__global__ void agg2_kernel(const int* __restrict__ csr_src, const int* __restrict__ rowp,
                            const float* __restrict__ hs2, const float* __restrict__ dis,
                            const float* __restrict__ b2, float* __restrict__ out, int N) {
    int b = blockIdx.x, t = threadIdx.x;
    int l = t & 15;
    int g = t >> 4;
    int nbase = b << NB_BITS;
    float bb = b2[0];
    for (int nl = g; nl < BN; nl += AGG_TPB / 16) {
        int n = nbase + nl;
        if (n >= N) continue;
        int r0 = rowp[n], r1 = rowp[n + 1];
        float a = 0.f;
        for (int r = r0 + l; r < r1; r += 16)
            a += hs2[__builtin_nontemporal_load(csr_src + r)];
        a += __shfl_xor(a, 1);
        a += __shfl_xor(a, 2);
        a += __shfl_xor(a, 4);
        a += __shfl_xor(a, 8);
        if (l == 0) out[n] = dis[n] * (a + hs2[n]) + bb;
    }
}

extern "C" void kernel_launch(void* const* d_in, const int* in_sizes, int n_in,
                              void* d_out, int out_size, void* d_ws, size_t ws_size,
                              hipStream_t stream) {
    const float* x = (const float*)d_in[0];
    const int* edge_index = (const int*)d_in[1];
    const float* W1 = (const float*)d_in[2];
    const float* b1 = (const float*)d_in[3];
    const float* W2 = (const float*)d_in[4];
    const float* b2 = (const float*)d_in[5];
    float* out = (float*)d_out;

    const int N = in_sizes[0] / 18;
    const int E = in_sizes[1] / 2;
    const int* src = edge_index;
    const int* dst = edge_index + E;
    const int NABUCKET = (N + BN - 1) / BN;    // 977 agg blocks
    const int NSBUCKET = (N + SBN - 1) / SBN;  // 489 sort bins

    // ws layout (4B words): pairs[E], csr_src[E], hs1a(8 fp16/node = 4N words),
    // hs1b(4N words), partial[N], hs2[N], dis[N], rowp[NSBUCKET*SBN+1],
    // bstart[NSB+1], cursor[NSB], bcnt[NSB]  ~= 45 MB
    int* ws = (int*)d_ws;
    int* pairs = ws;
    int* csr_src = pairs + (size_t)E;
    __half* hs1a = (__half*)(csr_src + (size_t)E);
    __half* hs1b = (__half*)((int*)(csr_src + (size_t)E) + 4 * (size_t)N);
    float* partial = (float*)((int*)(csr_src + (size_t)E) + 8 * (size_t)N);
    float* hs2 = partial + N;
    float* dis = hs2 + N;
    int* rowp = (int*)(dis + N);
    int* bstart = rowp + (size_t)NSBUCKET * SBN + 1;
    int* cursor = bstart + NSB + 1;
    int* bcnt = cursor + NSB;

    hipMemsetAsync(bcnt, 0, NSB * sizeof(int), stream);

    int binBlocks = (E + BIN_CHUNK - 1) / BIN_CHUNK;  // 489
    int nBlocksN = (N + 255) / 256;

    bhist_kernel<<<binBlocks, BIN_TPB, 0, stream>>>(dst, bcnt, E);
    bscan_kernel<<<1, NSB, 0, stream>>>(bcnt, bstart, cursor);
    bplace_kernel<<<binBlocks, BIN_TPB, 0, stream>>>(src, dst, cursor, pairs, E);
    csr_kernel<<<NSBUCKET, SBN, 0, stream>>>(pairs, bstart, rowp, csr_src, dis, N);
    h1_kernel<<<nBlocksN, 256, 0, stream>>>(x, W1, dis, hs1a, hs1b, N);
    agg1a_kernel<<<NABUCKET, AGG_TPB, 0, stream>>>(csr_src, rowp, hs1a, dis, b1, W2,
                                                   partial, N);
    agg1b_kernel<<<NABUCKET, AGG_TPB, 0, stream>>>(csr_src, rowp, hs1b, dis, b1, W2,
                                                   partial, hs2, N);
    agg2_kernel<<<NABUCKET, AGG_TPB, 0, stream>>>(csr_src, rowp, hs2, dis, b2, out, N);
}

// Round 19
// 251.648 us; speedup vs baseline: 1.1818x; 1.1818x over previous
//
#include <hip/hip_runtime.h>
#include <hip/hip_fp16.h>

// GCN 2-layer. N=250000, E=4000000, 18 -> 16 -> 1.
// R14: bisect R13's post-timing divergence. R13 (= R11 + bhists-reuse +
// h1-fused-into-csr) was correct on call 1 but deterministically wrong
// (3.3e-2, ~few misplaced edges) on calls 2+. Error signature implicates the
// pairs-placement path -> DROP the bhists reuse (bplace recomputes its own
// histogram, R11 form). KEEP only the h1-into-csr fusion (register-only
// arithmetic relocation, provably race-free). Single delta vs R11 baseline.
// agg1 FROZEN in R11 form (request-path bound at ~2.6TB/s, 58us).
//
// out[d] = dis[d] * (sum_{s->d} hs[s] + hs[d]) + bias, hs pre-scaled by dis.

#define NB_BITS 8
#define BN (1 << NB_BITS)       // 256 nodes per agg bucket (agg1 grid)
#define SB_BITS 9
#define SBN (1 << SB_BITS)      // 512 nodes per sort bin
#define NSB 512                 // padded bin count (489 used)
#define BIN_TPB 512
#define BIN_CHUNK 8192
#define AGG_TPB 512

// per-block LDS histogram of dst sort-bins -> global bcnt (R11 form)
__global__ void bhist_kernel(const int* __restrict__ dst, int* __restrict__ bcnt, int E) {
    __shared__ int cnt[NSB];
    int t = threadIdx.x;        // BIN_TPB == NSB == 512
    cnt[t] = 0;
    __syncthreads();
    int base = blockIdx.x * BIN_CHUNK;
    int end = min(base + BIN_CHUNK, E);
#pragma unroll 4
    for (int e = base + t; e < end; e += BIN_TPB)
        atomicAdd(&cnt[dst[e] >> SB_BITS], 1);
    __syncthreads();
    if (cnt[t] > 0) atomicAdd(&bcnt[t], cnt[t]);
}

// exclusive scan of bcnt[NSB] -> bstart, cursor
__global__ void bscan_kernel(const int* __restrict__ bcnt, int* __restrict__ bstart,
                             int* __restrict__ cursor) {
    __shared__ int s[NSB];
    int t = threadIdx.x;  // NSB threads
    int v = bcnt[t];
    s[t] = v;
    __syncthreads();
    for (int off = 1; off < NSB; off <<= 1) {
        int add = (t >= off) ? s[t - off] : 0;
        __syncthreads();
        s[t] += add;
        __syncthreads();
    }
    int excl = s[t] - v;
    bstart[t] = excl;
    cursor[t] = excl;
    if (t == NSB - 1) bstart[NSB] = s[t];
}

// place edges with block-local counting sort -> coalesced run writes.
// R11 form: recomputes its own histogram. pairs = (src<<9 | dst&511).
__global__ void bplace_kernel(const int* __restrict__ src, const int* __restrict__ dst,
                              int* __restrict__ cursor, int* __restrict__ pairs, int E) {
    __shared__ int cnt[NSB];
    __shared__ int lstart[NSB];
    __shared__ int lcur[NSB];
    __shared__ int gbase[NSB];
    __shared__ int lbuf[BIN_CHUNK];            // 32KB
    __shared__ unsigned short lbin[BIN_CHUNK]; // 16KB
    int t = threadIdx.x;
    int base = blockIdx.x * BIN_CHUNK;
    int end = min(base + BIN_CHUNK, E);
    cnt[t] = 0;
    __syncthreads();
#pragma unroll 4
    for (int e = base + t; e < end; e += BIN_TPB)
        atomicAdd(&cnt[dst[e] >> SB_BITS], 1);
    __syncthreads();
    // inclusive scan of cnt (Hillis-Steele in lstart)
    int v = cnt[t];
    lstart[t] = v;
    __syncthreads();
    for (int off = 1; off < NSB; off <<= 1) {
        int add = (t >= off) ? lstart[t - off] : 0;
        __syncthreads();
        lstart[t] += add;
        __syncthreads();
    }
    int excl = lstart[t] - v;   // own-index reads only below: no hazard
    lstart[t] = excl;
    lcur[t] = excl;
    gbase[t] = (v > 0) ? atomicAdd(&cursor[t], v) : 0;
    __syncthreads();
    // scatter into LDS in bin-sorted order
#pragma unroll 2
    for (int e = base + t; e < end; e += BIN_TPB) {
        int d = dst[e], s = src[e];
        int b = d >> SB_BITS;
        int pos = atomicAdd(&lcur[b], 1);
        lbuf[pos] = (s << SB_BITS) | (d & (SBN - 1));
        lbin[pos] = (unsigned short)b;
    }
    __syncthreads();
    // copy out: consecutive i within a bin -> consecutive global addresses
    int n = end - base;
#pragma unroll 4
    for (int i = t; i < n; i += BIN_TPB) {
        int b = lbin[i];
        pairs[gbase[b] + (i - lstart[b])] = lbuf[i];
    }
}

// per-bin CSR build + fused h1. Count per dst (int LDS atomics), scan, place
// srcs dst-sorted; emits rowp, csr_src, dis. Tail: thread t computes node
// nbase+t's hs1 row = fp16(x@W1 * dis) in registers and stores it (2x uint4).
// Tail reads only stable w[] (loaded+synced at start), x, and register dv:
// no race surface.
__global__ void csr_kernel(const int* __restrict__ pairs, const int* __restrict__ bstart,
                           int* __restrict__ rowp, int* __restrict__ csr_src,
                           float* __restrict__ dis, const float* __restrict__ x,
                           const float* __restrict__ W1, __half* __restrict__ hs1h,
                           int N) {
    __shared__ int cnt[SBN];
    __shared__ int tmp[SBN];
    __shared__ float w[18 * 16];
    int b = blockIdx.x, t = threadIdx.x;   // TPB == SBN == 512
    int s0 = bstart[b], s1 = bstart[b + 1];
    cnt[t] = 0;
    if (t < 18 * 16) w[t] = W1[t];
    __syncthreads();
#pragma unroll 4
    for (int e = s0 + t; e < s1; e += SBN)
        atomicAdd(&cnt[pairs[e] & (SBN - 1)], 1);
    __syncthreads();
    int v = cnt[t];
    tmp[t] = v;
    __syncthreads();
    for (int off = 1; off < SBN; off <<= 1) {
        int add = (t >= off) ? tmp[t - off] : 0;
        __syncthreads();
        tmp[t] += add;
        __syncthreads();
    }
    int nbase = b << SB_BITS;
    int start = s0 + tmp[t] - v;   // exclusive within bin, global offset
    rowp[nbase + t] = start;
    int n = nbase + t;
    float dv = rsqrtf((float)v + 1.0f);
    if (n < N) dis[n] = dv;
    cnt[t] = start;                // reuse as placement cursor
    if (t == 0) rowp[nbase + SBN] = s1;  // boundary (dup of next bin's first)
    __syncthreads();
#pragma unroll 4
    for (int e = s0 + t; e < s1; e += SBN) {
        int pv = pairs[e];
        int pos = atomicAdd(&cnt[pv & (SBN - 1)], 1);
        csr_src[pos] = pv >> SB_BITS;
    }
    // fused h1 tail: registers + stable w[] only, no sync needed
    if (n < N) {
        const float2* x2 = (const float2*)(x + (size_t)n * 18);
        float xv[18];
#pragma unroll
        for (int k = 0; k < 9; k++) {
            float2 vv = x2[k];
            xv[2 * k] = vv.x;
            xv[2 * k + 1] = vv.y;
        }
        float acc[16];
#pragma unroll
        for (int f = 0; f < 16; f++) acc[f] = 0.0f;
#pragma unroll
        for (int k = 0; k < 18; k++) {
            float xk = xv[k];
#pragma unroll
            for (int f = 0; f < 16; f++) acc[f] = fmaf(xk, w[k * 16 + f], acc[f]);
        }
        unsigned int u[8];
#pragma unroll
        for (int q = 0; q < 8; q++) {
            unsigned int lo = __half_as_ushort(__float2half_rn(acc[2 * q] * dv));
            unsigned int hi = __half_as_ushort(__float2half_rn(acc[2 * q + 1] * dv));
            u[q] = lo | (hi << 16);
        }
        uint4* outp = (uint4*)(hs1h + (size_t)n * 16);
        outp[0] = make_uint4(u[0], u[1], u[2], u[3]);
        outp[1] = make_uint4(u[4], u[5], u[6], u[7]);
    }
}

// layer-1: CSR, one node per 16-lane group, REGISTER accumulation (R11 form,
// FROZEN: at the random-line fetch-path rate ~2.6TB/s).
__global__ void agg1_kernel(const int* __restrict__ csr_src, const int* __restrict__ rowp,
                            const __half* __restrict__ hs1h, const float* __restrict__ dis,
                            const float* __restrict__ b1, const float* __restrict__ W2,
                            float* __restrict__ hs2, int N) {
    int b = blockIdx.x, t = threadIdx.x;
    int f = t & 15;
    int g = t >> 4;                 // 0..31 groups
    float bbf = b1[f], wwf = W2[f];
    int nbase = b << NB_BITS;
    for (int nl = g; nl < BN; nl += AGG_TPB / 16) {
        int n = nbase + nl;
        if (n >= N) continue;
        int r0 = rowp[n], r1 = rowp[n + 1];
        float a = 0.f;
#pragma unroll 4
        for (int r = r0; r < r1; ++r) {
            int s = csr_src[r];     // group-uniform broadcast load
            a += __half2float(hs1h[(size_t)s * 16 + f]);
        }
        float d = dis[n];
        float self = __half2float(hs1h[(size_t)n * 16 + f]);
        float p = fmaxf(d * (a + self) + bbf, 0.f) * wwf;
        p += __shfl_xor(p, 1);
        p += __shfl_xor(p, 2);
        p += __shfl_xor(p, 4);
        p += __shfl_xor(p, 8);
        if (f == 0) hs2[n] = p * d;
    }
}

// layer-2: CSR, one node per 16-lane group; lanes split the run, shfl reduce.
// hs2 is 1MB -> L2-resident gather.
__global__ void agg2_kernel(const int* __restrict__ csr_src, const int* __restrict__ rowp,
                            const float* __restrict__ hs2, const float* __restrict__ dis,
                            const float* __restrict__ b2, float* __restrict__ out, int N) {
    int b = blockIdx.x, t = threadIdx.x;
    int l = t & 15;
    int g = t >> 4;
    int nbase = b << NB_BITS;
    float bb = b2[0];
    for (int nl = g; nl < BN; nl += AGG_TPB / 16) {
        int n = nbase + nl;
        if (n >= N) continue;
        int r0 = rowp[n], r1 = rowp[n + 1];
        float a = 0.f;
        for (int r = r0 + l; r < r1; r += 16) a += hs2[csr_src[r]];
        a += __shfl_xor(a, 1);
        a += __shfl_xor(a, 2);
        a += __shfl_xor(a, 4);
        a += __shfl_xor(a, 8);
        if (l == 0) out[n] = dis[n] * (a + hs2[n]) + bb;
    }
}

extern "C" void kernel_launch(void* const* d_in, const int* in_sizes, int n_in,
                              void* d_out, int out_size, void* d_ws, size_t ws_size,
                              hipStream_t stream) {
    const float* x = (const float*)d_in[0];
    const int* edge_index = (const int*)d_in[1];
    const float* W1 = (const float*)d_in[2];
    const float* b1 = (const float*)d_in[3];
    const float* W2 = (const float*)d_in[4];
    const float* b2 = (const float*)d_in[5];
    float* out = (float*)d_out;

    const int N = in_sizes[0] / 18;
    const int E = in_sizes[1] / 2;
    const int* src = edge_index;
    const int* dst = edge_index + E;
    const int NABUCKET = (N + BN - 1) / BN;    // 977 agg blocks
    const int NSBUCKET = (N + SBN - 1) / SBN;  // 489 sort bins

    // ws layout (4B words), identical to R11: pairs[E], csr_src[E],
    // hs1h(16 fp16/node = 8N words), hs2[N], dis[N], rowp[NSBUCKET*SBN+1],
    // bstart[NSB+1], cursor[NSB], bcnt[NSB]  ~= 43 MB
    int* ws = (int*)d_ws;
    int* pairs = ws;
    int* csr_src = pairs + (size_t)E;
    __half* hs1h = (__half*)(csr_src + (size_t)E);
    float* hs2 = (float*)((int*)(csr_src + (size_t)E) + 8 * (size_t)N);
    float* dis = hs2 + N;
    int* rowp = (int*)(dis + N);
    int* bstart = rowp + (size_t)NSBUCKET * SBN + 1;
    int* cursor = bstart + NSB + 1;
    int* bcnt = cursor + NSB;

    hipMemsetAsync(bcnt, 0, NSB * sizeof(int), stream);

    int binBlocks = (E + BIN_CHUNK - 1) / BIN_CHUNK;  // 489

    bhist_kernel<<<binBlocks, BIN_TPB, 0, stream>>>(dst, bcnt, E);
    bscan_kernel<<<1, NSB, 0, stream>>>(bcnt, bstart, cursor);
    bplace_kernel<<<binBlocks, BIN_TPB, 0, stream>>>(src, dst, cursor, pairs, E);
    csr_kernel<<<NSBUCKET, SBN, 0, stream>>>(pairs, bstart, rowp, csr_src, dis,
                                             x, W1, hs1h, N);
    agg1_kernel<<<NABUCKET, AGG_TPB, 0, stream>>>(csr_src, rowp, hs1h, dis, b1, W2, hs2, N);
    agg2_kernel<<<NABUCKET, AGG_TPB, 0, stream>>>(csr_src, rowp, hs2, dis, b2, out, N);
}

// Round 21
// 246.733 us; speedup vs baseline: 1.2053x; 1.0199x over previous
//
#include <hip/hip_runtime.h>
#include <hip/hip_fp16.h>

// GCN 2-layer. N=250000, E=4000000, 18 -> 16 -> 1.
// R15: de-latency the binning chain. R14 (251.6us) = agg1 58us (frozen,
// request-path bound) + ~193us of sub-58us kernels. BW models say the chain
// should cost ~80us -> bplace/csr are barrier/issue-bound (18-barrier
// Hillis-Steele scans, 16-iter scalar edge loops). Changes vs R14:
//  1) wave-shfl exclusive scan (2 barriers, not 18) in bplace + csr
//  2) int4 edge streams (4 edges/thread/iter) in bhist + bplace
// All layouts, agg1 (58us), agg2, bscan identical to R14.
//
// out[d] = dis[d] * (sum_{s->d} hs[s] + hs[d]) + bias, hs pre-scaled by dis.

#define NB_BITS 8
#define BN (1 << NB_BITS)       // 256 nodes per agg bucket (agg1 grid)
#define SB_BITS 9
#define SBN (1 << SB_BITS)      // 512 nodes per sort bin
#define NSB 512                 // padded bin count (489 used)
#define BIN_TPB 512
#define BIN_CHUNK 8192
#define AGG_TPB 512

// exclusive scan of v over 512 threads: wave shfl scan + 8-partial combine.
// 2 barriers. warpsums must be LDS int[8].
__device__ __forceinline__ int exscan512(int v, int* warpsums, int t) {
    int lane = t & 63, w = t >> 6;
    int x = v;
#pragma unroll
    for (int off = 1; off < 64; off <<= 1) {
        int y = __shfl_up(x, off);
        if (lane >= off) x += y;
    }
    if (lane == 63) warpsums[w] = x;
    __syncthreads();
    if (w == 0) {
        int s = (lane < 8) ? warpsums[lane] : 0;
#pragma unroll
        for (int off = 1; off < 8; off <<= 1) {
            int y = __shfl_up(s, off);
            if (lane >= off) s += y;
        }
        if (lane < 8) warpsums[lane] = s;
    }
    __syncthreads();
    int base = (w > 0) ? warpsums[w - 1] : 0;
    return base + x - v;  // exclusive
}

// per-block LDS histogram of dst sort-bins -> global bcnt. int4 edge stream.
__global__ void bhist_kernel(const int* __restrict__ dst, int* __restrict__ bcnt, int E) {
    __shared__ int cnt[NSB];
    int t = threadIdx.x;        // BIN_TPB == NSB == 512
    cnt[t] = 0;
    __syncthreads();
    int base = blockIdx.x * BIN_CHUNK;
    int end = min(base + BIN_CHUNK, E);
    if (end - base == BIN_CHUNK) {
        const int4* d4 = (const int4*)(dst + base);
#pragma unroll
        for (int i = 0; i < BIN_CHUNK / (BIN_TPB * 4); i++) {
            int4 v = d4[t + i * BIN_TPB];
            atomicAdd(&cnt[v.x >> SB_BITS], 1);
            atomicAdd(&cnt[v.y >> SB_BITS], 1);
            atomicAdd(&cnt[v.z >> SB_BITS], 1);
            atomicAdd(&cnt[v.w >> SB_BITS], 1);
        }
    } else {
        for (int e = base + t; e < end; e += BIN_TPB)
            atomicAdd(&cnt[dst[e] >> SB_BITS], 1);
    }
    __syncthreads();
    if (cnt[t] > 0) atomicAdd(&bcnt[t], cnt[t]);
}

// exclusive scan of bcnt[NSB] -> bstart, cursor (1 block; cost negligible)
__global__ void bscan_kernel(const int* __restrict__ bcnt, int* __restrict__ bstart,
                             int* __restrict__ cursor) {
    __shared__ int warpsums[8];
    int t = threadIdx.x;  // NSB threads
    int v = bcnt[t];
    int excl = exscan512(v, warpsums, t);
    bstart[t] = excl;
    cursor[t] = excl;
    if (t == NSB - 1) bstart[NSB] = excl + v;
}

// place edges with block-local counting sort -> coalesced run writes.
// int4 streams, wave-shfl scan. pairs = (src<<9 | dst&511).
__global__ void bplace_kernel(const int* __restrict__ src, const int* __restrict__ dst,
                              int* __restrict__ cursor, int* __restrict__ pairs, int E) {
    __shared__ int cnt[NSB];
    __shared__ int lstart[NSB];
    __shared__ int lcur[NSB];
    __shared__ int gbase[NSB];
    __shared__ int warpsums[8];
    __shared__ int lbuf[BIN_CHUNK];            // 32KB
    __shared__ unsigned short lbin[BIN_CHUNK]; // 16KB
    int t = threadIdx.x;
    int base = blockIdx.x * BIN_CHUNK;
    int end = min(base + BIN_CHUNK, E);
    int full = (end - base == BIN_CHUNK);
    cnt[t] = 0;
    __syncthreads();
    if (full) {
        const int4* d4 = (const int4*)(dst + base);
#pragma unroll
        for (int i = 0; i < BIN_CHUNK / (BIN_TPB * 4); i++) {
            int4 v = d4[t + i * BIN_TPB];
            atomicAdd(&cnt[v.x >> SB_BITS], 1);
            atomicAdd(&cnt[v.y >> SB_BITS], 1);
            atomicAdd(&cnt[v.z >> SB_BITS], 1);
            atomicAdd(&cnt[v.w >> SB_BITS], 1);
        }
    } else {
        for (int e = base + t; e < end; e += BIN_TPB)
            atomicAdd(&cnt[dst[e] >> SB_BITS], 1);
    }
    __syncthreads();
    int v = cnt[t];
    int excl = exscan512(v, warpsums, t);   // 2 barriers
    lstart[t] = excl;
    lcur[t] = excl;
    gbase[t] = (v > 0) ? atomicAdd(&cursor[t], v) : 0;
    __syncthreads();
    // scatter into LDS in bin-sorted order
    if (full) {
        const int4* s4 = (const int4*)(src + base);
        const int4* d4 = (const int4*)(dst + base);
#pragma unroll
        for (int i = 0; i < BIN_CHUNK / (BIN_TPB * 4); i++) {
            int4 dv = d4[t + i * BIN_TPB];
            int4 sv = s4[t + i * BIN_TPB];
            int b0 = dv.x >> SB_BITS, p0 = atomicAdd(&lcur[b0], 1);
            lbuf[p0] = (sv.x << SB_BITS) | (dv.x & (SBN - 1));
            lbin[p0] = (unsigned short)b0;
            int b1 = dv.y >> SB_BITS, p1 = atomicAdd(&lcur[b1], 1);
            lbuf[p1] = (sv.y << SB_BITS) | (dv.y & (SBN - 1));
            lbin[p1] = (unsigned short)b1;
            int b2 = dv.z >> SB_BITS, p2 = atomicAdd(&lcur[b2], 1);
            lbuf[p2] = (sv.z << SB_BITS) | (dv.z & (SBN - 1));
            lbin[p2] = (unsigned short)b2;
            int b3 = dv.w >> SB_BITS, p3 = atomicAdd(&lcur[b3], 1);
            lbuf[p3] = (sv.w << SB_BITS) | (dv.w & (SBN - 1));
            lbin[p3] = (unsigned short)b3;
        }
    } else {
        for (int e = base + t; e < end; e += BIN_TPB) {
            int d = dst[e], s = src[e];
            int b = d >> SB_BITS;
            int pos = atomicAdd(&lcur[b], 1);
            lbuf[pos] = (s << SB_BITS) | (d & (SBN - 1));
            lbin[pos] = (unsigned short)b;
        }
    }
    __syncthreads();
    // copy out: consecutive i within a bin -> consecutive global addresses
    int n = end - base;
#pragma unroll 4
    for (int i = t; i < n; i += BIN_TPB) {
        int b = lbin[i];
        pairs[gbase[b] + (i - lstart[b])] = lbuf[i];
    }
}

// per-bin CSR build + fused h1. Wave-shfl scan (2 barriers). Tail: thread t
// computes node nbase+t's hs1 row = fp16(x@W1 * dis), stores 2x uint4.
__global__ void csr_kernel(const int* __restrict__ pairs, const int* __restrict__ bstart,
                           int* __restrict__ rowp, int* __restrict__ csr_src,
                           float* __restrict__ dis, const float* __restrict__ x,
                           const float* __restrict__ W1, __half* __restrict__ hs1h,
                           int N) {
    __shared__ int cnt[SBN];
    __shared__ int warpsums[8];
    __shared__ float w[18 * 16];
    int b = blockIdx.x, t = threadIdx.x;   // TPB == SBN == 512
    int s0 = bstart[b], s1 = bstart[b + 1];
    cnt[t] = 0;
    if (t < 18 * 16) w[t] = W1[t];
    __syncthreads();
#pragma unroll 4
    for (int e = s0 + t; e < s1; e += SBN)
        atomicAdd(&cnt[pairs[e] & (SBN - 1)], 1);
    __syncthreads();
    int v = cnt[t];
    int excl = exscan512(v, warpsums, t);   // 2 barriers
    int nbase = b << SB_BITS;
    int start = s0 + excl;         // exclusive within bin, global offset
    rowp[nbase + t] = start;
    int n = nbase + t;
    float dv = rsqrtf((float)v + 1.0f);
    if (n < N) dis[n] = dv;
    __syncthreads();               // order cnt reuse after count-phase reads
    cnt[t] = start;                // reuse as placement cursor
    if (t == 0) rowp[nbase + SBN] = s1;  // boundary (dup of next bin's first)
    __syncthreads();
#pragma unroll 4
    for (int e = s0 + t; e < s1; e += SBN) {
        int pv = pairs[e];
        int pos = atomicAdd(&cnt[pv & (SBN - 1)], 1);
        csr_src[pos] = pv >> SB_BITS;
    }
    // fused h1 tail: registers + stable w[] only, no sync needed
    if (n < N) {
        const float2* x2 = (const float2*)(x + (size_t)n * 18);
        float xv[18];
#pragma unroll
        for (int k = 0; k < 9; k++) {
            float2 vv = x2[k];
            xv[2 * k] = vv.x;
            xv[2 * k + 1] = vv.y;
        }
        float acc[16];
#pragma unroll
        for (int f = 0; f < 16; f++) acc[f] = 0.0f;
#pragma unroll
        for (int k = 0; k < 18; k++) {
            float xk = xv[k];
#pragma unroll
            for (int f = 0; f < 16; f++) acc[f] = fmaf(xk, w[k * 16 + f], acc[f]);
        }
        unsigned int u[8];
#pragma unroll
        for (int q = 0; q < 8; q++) {
            unsigned int lo = __half_as_ushort(__float2half_rn(acc[2 * q] * dv));
            unsigned int hi = __half_as_ushort(__float2half_rn(acc[2 * q + 1] * dv));
            u[q] = lo | (hi << 16);
        }
        uint4* outp = (uint4*)(hs1h + (size_t)n * 16);
        outp[0] = make_uint4(u[0], u[1], u[2], u[3]);
        outp[1] = make_uint4(u[4], u[5], u[6], u[7]);
    }
}

// layer-1: CSR, one node per 16-lane group, REGISTER accumulation (R11 form,
// FROZEN: at the random-line fetch-path rate ~2.6TB/s).
__global__ void agg1_kernel(const int* __restrict__ csr_src, const int* __restrict__ rowp,
                            const __half* __restrict__ hs1h, const float* __restrict__ dis,
                            const float* __restrict__ b1, const float* __restrict__ W2,
                            float* __restrict__ hs2, int N) {
    int b = blockIdx.x, t = threadIdx.x;
    int f = t & 15;
    int g = t >> 4;                 // 0..31 groups
    float bbf = b1[f], wwf = W2[f];
    int nbase = b << NB_BITS;
    for (int nl = g; nl < BN; nl += AGG_TPB / 16) {
        int n = nbase + nl;
        if (n >= N) continue;
        int r0 = rowp[n], r1 = rowp[n + 1];
        float a = 0.f;
#pragma unroll 4
        for (int r = r0; r < r1; ++r) {
            int s = csr_src[r];     // group-uniform broadcast load
            a += __half2float(hs1h[(size_t)s * 16 + f]);
        }
        float d = dis[n];
        float self = __half2float(hs1h[(size_t)n * 16 + f]);
        float p = fmaxf(d * (a + self) + bbf, 0.f) * wwf;
        p += __shfl_xor(p, 1);
        p += __shfl_xor(p, 2);
        p += __shfl_xor(p, 4);
        p += __shfl_xor(p, 8);
        if (f == 0) hs2[n] = p * d;
    }
}

// layer-2: CSR, one node per 16-lane group; lanes split the run, shfl reduce.
// hs2 is 1MB -> L2-resident gather.
__global__ void agg2_kernel(const int* __restrict__ csr_src, const int* __restrict__ rowp,
                            const float* __restrict__ hs2, const float* __restrict__ dis,
                            const float* __restrict__ b2, float* __restrict__ out, int N) {
    int b = blockIdx.x, t = threadIdx.x;
    int l = t & 15;
    int g = t >> 4;
    int nbase = b << NB_BITS;
    float bb = b2[0];
    for (int nl = g; nl < BN; nl += AGG_TPB / 16) {
        int n = nbase + nl;
        if (n >= N) continue;
        int r0 = rowp[n], r1 = rowp[n + 1];
        float a = 0.f;
        for (int r = r0 + l; r < r1; r += 16) a += hs2[csr_src[r]];
        a += __shfl_xor(a, 1);
        a += __shfl_xor(a, 2);
        a += __shfl_xor(a, 4);
        a += __shfl_xor(a, 8);
        if (l == 0) out[n] = dis[n] * (a + hs2[n]) + bb;
    }
}

extern "C" void kernel_launch(void* const* d_in, const int* in_sizes, int n_in,
                              void* d_out, int out_size, void* d_ws, size_t ws_size,
                              hipStream_t stream) {
    const float* x = (const float*)d_in[0];
    const int* edge_index = (const int*)d_in[1];
    const float* W1 = (const float*)d_in[2];
    const float* b1 = (const float*)d_in[3];
    const float* W2 = (const float*)d_in[4];
    const float* b2 = (const float*)d_in[5];
    float* out = (float*)d_out;

    const int N = in_sizes[0] / 18;
    const int E = in_sizes[1] / 2;
    const int* src = edge_index;
    const int* dst = edge_index + E;
    const int NABUCKET = (N + BN - 1) / BN;    // 977 agg blocks
    const int NSBUCKET = (N + SBN - 1) / SBN;  // 489 sort bins

    // ws layout (4B words), identical to R14: pairs[E], csr_src[E],
    // hs1h(16 fp16/node = 8N words), hs2[N], dis[N], rowp[NSBUCKET*SBN+1],
    // bstart[NSB+1], cursor[NSB], bcnt[NSB]  ~= 43 MB
    int* ws = (int*)d_ws;
    int* pairs = ws;
    int* csr_src = pairs + (size_t)E;
    __half* hs1h = (__half*)(csr_src + (size_t)E);
    float* hs2 = (float*)((int*)(csr_src + (size_t)E) + 8 * (size_t)N);
    float* dis = hs2 + N;
    int* rowp = (int*)(dis + N);
    int* bstart = rowp + (size_t)NSBUCKET * SBN + 1;
    int* cursor = bstart + NSB + 1;
    int* bcnt = cursor + NSB;

    hipMemsetAsync(bcnt, 0, NSB * sizeof(int), stream);

    int binBlocks = (E + BIN_CHUNK - 1) / BIN_CHUNK;  // 489

    bhist_kernel<<<binBlocks, BIN_TPB, 0, stream>>>(dst, bcnt, E);
    bscan_kernel<<<1, NSB, 0, stream>>>(bcnt, bstart, cursor);
    bplace_kernel<<<binBlocks, BIN_TPB, 0, stream>>>(src, dst, cursor, pairs, E);
    csr_kernel<<<NSBUCKET, SBN, 0, stream>>>(pairs, bstart, rowp, csr_src, dis,
                                             x, W1, hs1h, N);
    agg1_kernel<<<NABUCKET, AGG_TPB, 0, stream>>>(csr_src, rowp, hs1h, dis, b1, W2, hs2, N);
    agg2_kernel<<<NABUCKET, AGG_TPB, 0, stream>>>(csr_src, rowp, hs2, dis, b2, out, N);
}